// Round 1
// baseline (769.154 us; speedup 1.0000x reference)
//
#include <hip/hip_runtime.h>
#include <math.h>

#define Bq 512
#define Cq 80
#define Fq 768
#define Hq 256

constexpr float EPS   = 1e-5f;
constexpr float THR   = 0.5f;
constexpr float SCALE = 0.0625f;   // 1/sqrt(256)

__device__ __forceinline__ float waveReduceSum(float v) {
#pragma unroll
  for (int m = 32; m >= 1; m >>= 1) v += __shfl_xor(v, m);
  return v;
}

// ---------------------------------------------------------------------------
// K1: vis = relu(LN(vf @ Wp + bp))    (B,H)
// one block per b, 256 threads (thread = output h)
// ---------------------------------------------------------------------------
__global__ __launch_bounds__(256) void k_visproj(
    const float* __restrict__ vf, const float* __restrict__ Wp,
    const float* __restrict__ bp, const float* __restrict__ gp,
    const float* __restrict__ bep, float* __restrict__ vis) {
  __shared__ float vfs[Fq];
  __shared__ float red[4];
  const int b = blockIdx.x, h = threadIdx.x;
  for (int i = h; i < Fq; i += 256) vfs[i] = vf[b * Fq + i];
  __syncthreads();

  float acc = bp[h];
  for (int f = 0; f < Fq; f++) acc = fmaf(vfs[f], Wp[f * Hq + h], acc);

  // LayerNorm over the 256 h-values (one per thread)
  const int w = h >> 6, lane = h & 63;
  float s = waveReduceSum(acc);
  if (lane == 0) red[w] = s;
  __syncthreads();
  const float mean = (red[0] + red[1] + red[2] + red[3]) * (1.0f / Hq);
  __syncthreads();
  const float d = acc - mean;
  s = waveReduceSum(d * d);
  if (lane == 0) red[w] = s;
  __syncthreads();
  const float var = (red[0] + red[1] + red[2] + red[3]) * (1.0f / Hq);
  float y = d * (1.0f / sqrtf(var + EPS)) * gp[h] + bep[h];
  vis[b * Hq + h] = fmaxf(y, 0.0f);
}

// ---------------------------------------------------------------------------
// K2 (fused): for class c, 16 batch rows:
//   z = vis @ Wc[c] + bc[c];  cf = relu(LN(z));  X' = x + cf  (into LDS)
//   Q,K,V = X' @ {Wq,Wk,Wv} + bias        (written to ws)
// grid = (B/16, C), block 256 (thread = output h, 16 rows each)
// ---------------------------------------------------------------------------
__global__ __launch_bounds__(256) void k_feat_qkv(
    const float* __restrict__ vis, const float* __restrict__ x,
    const float* __restrict__ Wc, const float* __restrict__ bc,
    const float* __restrict__ gc, const float* __restrict__ bec,
    const float* __restrict__ Wq, const float* __restrict__ bq,
    const float* __restrict__ Wk, const float* __restrict__ bk,
    const float* __restrict__ Wv, const float* __restrict__ bv,
    float* __restrict__ Q, float* __restrict__ K_, float* __restrict__ V) {
  const int c = blockIdx.y;
  const int b0 = blockIdx.x * 16;
  const int h = threadIdx.x;
  const int w = h >> 6, lane = h & 63;

  __shared__ float Xs[16][Hq];   // 16 KB
  __shared__ float red[4][16];
  __shared__ float rstat[16];

  // ---- phase 1: class-extractor GEMM ----
  float acc[16];
#pragma unroll
  for (int t = 0; t < 16; t++) acc[t] = 0.f;
  const float* wc = Wc + (size_t)c * Hq * Hq;
  for (int k = 0; k < Hq; k += 4) {
    const float w0 = wc[(k + 0) * Hq + h];
    const float w1 = wc[(k + 1) * Hq + h];
    const float w2 = wc[(k + 2) * Hq + h];
    const float w3 = wc[(k + 3) * Hq + h];
#pragma unroll
    for (int t = 0; t < 16; t++) {
      const float4 vv = *reinterpret_cast<const float4*>(vis + (b0 + t) * Hq + k);
      acc[t] = fmaf(vv.x, w0, fmaf(vv.y, w1, fmaf(vv.z, w2, fmaf(vv.w, w3, acc[t]))));
    }
  }
  const float bcv = bc[c * Hq + h];
#pragma unroll
  for (int t = 0; t < 16; t++) acc[t] += bcv;

  // ---- per-row LayerNorm (16 rows, reduce over 256 threads) ----
#pragma unroll
  for (int t = 0; t < 16; t++) {
    const float s = waveReduceSum(acc[t]);
    if (lane == 0) red[w][t] = s;
  }
  __syncthreads();
  if (h < 16) rstat[h] = (red[0][h] + red[1][h] + red[2][h] + red[3][h]) * (1.0f / Hq);
  __syncthreads();
#pragma unroll
  for (int t = 0; t < 16; t++) acc[t] -= rstat[t];
  __syncthreads();   // everyone done reading rstat(mean) before overwrite
#pragma unroll
  for (int t = 0; t < 16; t++) {
    const float s = waveReduceSum(acc[t] * acc[t]);
    if (lane == 0) red[w][t] = s;
  }
  __syncthreads();
  if (h < 16) rstat[h] = (red[0][h] + red[1][h] + red[2][h] + red[3][h]) * (1.0f / Hq);
  __syncthreads();

  const float gcv = gc[c * Hq + h], becv = bec[c * Hq + h];
#pragma unroll
  for (int t = 0; t < 16; t++) {
    const float inv = 1.0f / sqrtf(rstat[t] + EPS);
    float y = acc[t] * inv * gcv + becv;
    y = fmaxf(y, 0.0f);
    const size_t idx = ((size_t)(b0 + t) * Cq + c) * Hq + h;
    Xs[t][h] = x[idx] + y;
  }
  __syncthreads();

  // ---- phase 2: Q,K,V projections from LDS ----
  float aq[16], ak[16], av[16];
#pragma unroll
  for (int t = 0; t < 16; t++) { aq[t] = 0.f; ak[t] = 0.f; av[t] = 0.f; }
  for (int k = 0; k < Hq; k += 4) {
    const float q0 = Wq[(k + 0) * Hq + h], q1 = Wq[(k + 1) * Hq + h];
    const float q2 = Wq[(k + 2) * Hq + h], q3 = Wq[(k + 3) * Hq + h];
    const float k0 = Wk[(k + 0) * Hq + h], k1 = Wk[(k + 1) * Hq + h];
    const float k2 = Wk[(k + 2) * Hq + h], k3 = Wk[(k + 3) * Hq + h];
    const float v0 = Wv[(k + 0) * Hq + h], v1 = Wv[(k + 1) * Hq + h];
    const float v2 = Wv[(k + 2) * Hq + h], v3 = Wv[(k + 3) * Hq + h];
#pragma unroll
    for (int t = 0; t < 16; t++) {
      const float4 xv = *reinterpret_cast<const float4*>(&Xs[t][k]);
      aq[t] = fmaf(xv.x, q0, fmaf(xv.y, q1, fmaf(xv.z, q2, fmaf(xv.w, q3, aq[t]))));
      ak[t] = fmaf(xv.x, k0, fmaf(xv.y, k1, fmaf(xv.z, k2, fmaf(xv.w, k3, ak[t]))));
      av[t] = fmaf(xv.x, v0, fmaf(xv.y, v1, fmaf(xv.z, v2, fmaf(xv.w, v3, av[t]))));
    }
  }
  const float bqv = bq[h], bkv = bk[h], bvv = bv[h];
#pragma unroll
  for (int t = 0; t < 16; t++) {
    const size_t r = (size_t)(b0 + t) * Cq + c;
    Q[r * Hq + h]  = aq[t] + bqv;
    K_[r * Hq + h] = ak[t] + bkv;
    V[r * Hq + h]  = av[t] + bvv;
  }
}

// ---------------------------------------------------------------------------
// K3: per-batch attention.  scores = (QK^T)*SCALE, hard-threshold mask,
// label mask, softmax, O = attn @ V.   O may alias Q (reads finish first).
// grid = B, block 256 arranged 16x16, each thread: 5x5 score tile.
// ---------------------------------------------------------------------------
__global__ __launch_bounds__(256) void k_attn(
    const float* __restrict__ Q, const float* __restrict__ K_,
    const float* __restrict__ V, const int* __restrict__ labels,
    float* __restrict__ O) {
  // smem layout: [attn 80*81][scratch: qs 80*33 | ks 80*33]  (vs aliases qs)
  __shared__ float sm[80 * 81 + 2 * 80 * 33];
  float* attn_s = sm;                  // [80][81]
  float* qs = sm + 80 * 81;            // [80][33]
  float* ks = qs + 80 * 33;            // [80][33]
  float* vs = qs;                      // [80][64], reused after scores

  const int b = blockIdx.x;
  const int t = threadIdx.x, tx = t & 15, ty = t >> 4;
  const float* Qb = Q + (size_t)b * Cq * Hq;
  const float* Kb = K_ + (size_t)b * Cq * Hq;

  float s[5][5];
#pragma unroll
  for (int i = 0; i < 5; i++)
#pragma unroll
    for (int j = 0; j < 5; j++) s[i][j] = 0.f;

  for (int kk = 0; kk < Hq; kk += 32) {
    for (int i = t; i < 80 * 32; i += 256) {
      const int row = i >> 5, col = i & 31;
      qs[row * 33 + col] = Qb[row * Hq + kk + col];
      ks[row * 33 + col] = Kb[row * Hq + kk + col];
    }
    __syncthreads();
    for (int k = 0; k < 32; k++) {
      float qv[5], kv[5];
#pragma unroll
      for (int i = 0; i < 5; i++) qv[i] = qs[(ty + 16 * i) * 33 + k];
#pragma unroll
      for (int j = 0; j < 5; j++) kv[j] = ks[(tx + 16 * j) * 33 + k];
#pragma unroll
      for (int i = 0; i < 5; i++)
#pragma unroll
        for (int j = 0; j < 5; j++) s[i][j] = fmaf(qv[i], kv[j], s[i][j]);
    }
    __syncthreads();
  }

  // mask + label mask
  float lm[5];
#pragma unroll
  for (int j = 0; j < 5; j++)
    lm[j] = (float)labels[b * Cq + tx + 16 * j] * 0.8f + 0.2f;
#pragma unroll
  for (int i = 0; i < 5; i++)
#pragma unroll
    for (int j = 0; j < 5; j++) {
      float v = s[i][j] * SCALE;
      v = (v > THR) ? v : 0.0f;
      s[i][j] = v * lm[j];
    }

  // softmax along d (spread over 16 lanes x 5 j's); rows stay in 16-lane group
#pragma unroll
  for (int i = 0; i < 5; i++) {
    float m = s[i][0];
#pragma unroll
    for (int j = 1; j < 5; j++) m = fmaxf(m, s[i][j]);
#pragma unroll
    for (int msk = 8; msk >= 1; msk >>= 1) m = fmaxf(m, __shfl_xor(m, msk));
    float sum = 0.f;
#pragma unroll
    for (int j = 0; j < 5; j++) {
      const float e = expf(s[i][j] - m);
      s[i][j] = e;
      sum += e;
    }
#pragma unroll
    for (int msk = 8; msk >= 1; msk >>= 1) sum += __shfl_xor(sum, msk);
    const float inv = 1.0f / sum;
#pragma unroll
    for (int j = 0; j < 5; j++)
      attn_s[(ty + 16 * i) * 81 + tx + 16 * j] = s[i][j] * inv;
  }
  __syncthreads();

  // O = attn @ V, V staged in 64-col chunks
  const float* Vb = V + (size_t)b * Cq * Hq;
  float* Ob = O + (size_t)b * Cq * Hq;
  for (int hc = 0; hc < 4; hc++) {
    const int h0 = hc * 64;
    for (int i = t; i < 80 * 64; i += 256) {
      const int row = i >> 6, col = i & 63;
      vs[row * 64 + col] = Vb[row * Hq + h0 + col];
    }
    __syncthreads();
    float o[5][4];
#pragma unroll
    for (int i = 0; i < 5; i++)
#pragma unroll
      for (int jj = 0; jj < 4; jj++) o[i][jj] = 0.f;
    for (int d = 0; d < Cq; d++) {
      float av[5], vv[4];
#pragma unroll
      for (int i = 0; i < 5; i++) av[i] = attn_s[(ty + 16 * i) * 81 + d];
#pragma unroll
      for (int jj = 0; jj < 4; jj++) vv[jj] = vs[d * 64 + tx + 16 * jj];
#pragma unroll
      for (int i = 0; i < 5; i++)
#pragma unroll
        for (int jj = 0; jj < 4; jj++) o[i][jj] = fmaf(av[i], vv[jj], o[i][jj]);
    }
#pragma unroll
    for (int i = 0; i < 5; i++)
#pragma unroll
      for (int jj = 0; jj < 4; jj++)
        Ob[(ty + 16 * i) * Hq + h0 + tx + 16 * jj] = o[i][jj];
    __syncthreads();
  }
}

// ---------------------------------------------------------------------------
// K4: out = O @ Wo + bo   (B*C rows)
// grid = B*C/16, block 256 (thread = col h, 16 rows)
// ---------------------------------------------------------------------------
__global__ __launch_bounds__(256) void k_oproj(
    const float* __restrict__ O, const float* __restrict__ Wo,
    const float* __restrict__ bo, float* __restrict__ out) {
  const int r0 = blockIdx.x * 16;
  const int h = threadIdx.x;
  float acc[16];
#pragma unroll
  for (int t = 0; t < 16; t++) acc[t] = 0.f;
  for (int k = 0; k < Hq; k += 4) {
    const float w0 = Wo[(k + 0) * Hq + h];
    const float w1 = Wo[(k + 1) * Hq + h];
    const float w2 = Wo[(k + 2) * Hq + h];
    const float w3 = Wo[(k + 3) * Hq + h];
#pragma unroll
    for (int t = 0; t < 16; t++) {
      const float4 xv = *reinterpret_cast<const float4*>(O + (size_t)(r0 + t) * Hq + k);
      acc[t] = fmaf(xv.x, w0, fmaf(xv.y, w1, fmaf(xv.z, w2, fmaf(xv.w, w3, acc[t]))));
    }
  }
  const float bov = bo[h];
#pragma unroll
  for (int t = 0; t < 16; t++)
    out[(size_t)(r0 + t) * Hq + h] = acc[t] + bov;
}

// ---------------------------------------------------------------------------
extern "C" void kernel_launch(void* const* d_in, const int* in_sizes, int n_in,
                              void* d_out, int out_size, void* d_ws, size_t ws_size,
                              hipStream_t stream) {
  const float* x   = (const float*)d_in[0];
  const float* vf  = (const float*)d_in[1];
  const int*   lab = (const int*)d_in[2];
  const float* Wp  = (const float*)d_in[3];
  const float* bp  = (const float*)d_in[4];
  const float* gp  = (const float*)d_in[5];
  const float* bep = (const float*)d_in[6];
  const float* Wc  = (const float*)d_in[7];
  const float* bc  = (const float*)d_in[8];
  const float* gc  = (const float*)d_in[9];
  const float* bec = (const float*)d_in[10];
  const float* Wq  = (const float*)d_in[11];
  const float* bq  = (const float*)d_in[12];
  const float* Wk  = (const float*)d_in[13];
  const float* bk  = (const float*)d_in[14];
  const float* Wv  = (const float*)d_in[15];
  const float* bv  = (const float*)d_in[16];
  const float* Wo  = (const float*)d_in[17];
  const float* bo  = (const float*)d_in[18];
  float* out = (float*)d_out;

  float* ws  = (float*)d_ws;
  const size_t NROW = (size_t)Bq * Cq * Hq;    // 10,485,760
  float* vis = ws;                              // B*H
  float* Q   = ws + (size_t)Bq * Hq;            // B*C*H
  float* K_  = Q + NROW;                        // B*C*H
  float* V   = K_ + NROW;                       // B*C*H
  float* O   = Q;                               // alias: Q dead before O written

  k_visproj<<<Bq, 256, 0, stream>>>(vf, Wp, bp, gp, bep, vis);
  k_feat_qkv<<<dim3(Bq / 16, Cq), 256, 0, stream>>>(vis, x, Wc, bc, gc, bec,
                                                    Wq, bq, Wk, bk, Wv, bv,
                                                    Q, K_, V);
  k_attn<<<Bq, 256, 0, stream>>>(Q, K_, V, lab, O);
  k_oproj<<<(Bq * Cq) / 16, 256, 0, stream>>>(O, Wo, bo, out);
}

// Round 2
// 547.229 us; speedup vs baseline: 1.4055x; 1.4055x over previous
//
#include <hip/hip_runtime.h>
#include <hip/hip_bf16.h>
#include <math.h>

#define Bq 512
#define Cq 80
#define Fq 768
#define Hq 256
#define Rq (Bq*Cq)

constexpr float EPS   = 1e-5f;
constexpr float THR   = 0.5f;
constexpr float SCALE = 0.0625f;   // 1/sqrt(256)

using f32x4 = __attribute__((ext_vector_type(4))) float;
using s16x8 = __attribute__((ext_vector_type(8))) short;
using s16x4 = __attribute__((ext_vector_type(4))) short;

__device__ __forceinline__ float waveReduceSum(float v) {
#pragma unroll
  for (int m = 32; m >= 1; m >>= 1) v += __shfl_xor(v, m);
  return v;
}

__device__ __forceinline__ float bfu(unsigned short v) {
  return __uint_as_float(((unsigned)v) << 16);
}

__device__ __forceinline__ unsigned short f2bf(float f) {
  __hip_bfloat16 h = __float2bfloat16(f);   // RNE
  return *reinterpret_cast<unsigned short*>(&h);
}

// ---------------------------------------------------------------------------
// K1: vis = relu(LN(vf @ Wp + bp)) -> split bf16 hi/lo
// ---------------------------------------------------------------------------
__global__ __launch_bounds__(256) void k_visproj(
    const float* __restrict__ vf, const float* __restrict__ Wp,
    const float* __restrict__ bp, const float* __restrict__ gp,
    const float* __restrict__ bep,
    unsigned short* __restrict__ vish, unsigned short* __restrict__ visl) {
  __shared__ float vfs[Fq];
  __shared__ float red[4];
  const int b = blockIdx.x, h = threadIdx.x;
  for (int i = h; i < Fq; i += 256) vfs[i] = vf[b * Fq + i];
  __syncthreads();

  float acc = bp[h];
  for (int f = 0; f < Fq; f++) acc = fmaf(vfs[f], Wp[f * Hq + h], acc);

  const int w = h >> 6, lane = h & 63;
  float s = waveReduceSum(acc);
  if (lane == 0) red[w] = s;
  __syncthreads();
  const float mean = (red[0] + red[1] + red[2] + red[3]) * (1.0f / Hq);
  __syncthreads();
  const float d = acc - mean;
  s = waveReduceSum(d * d);
  if (lane == 0) red[w] = s;
  __syncthreads();
  const float var = (red[0] + red[1] + red[2] + red[3]) * (1.0f / Hq);
  float y = d * rsqrtf(var + EPS) * gp[h] + bep[h];
  y = fmaxf(y, 0.0f);
  const unsigned short hb = f2bf(y);
  vish[b * Hq + h] = hb;
  visl[b * Hq + h] = f2bf(y - bfu(hb));
}

// ---------------------------------------------------------------------------
// M = Wq @ Wk^T ; w1 = Wq@bk ; w2 = Wk@bq ; cqk = bq.bk
// grid = Hq blocks (row i), 256 threads (col j)
// ---------------------------------------------------------------------------
__global__ __launch_bounds__(256) void k_matmulM(
    const float* __restrict__ Wq, const float* __restrict__ Wk,
    const float* __restrict__ bq, const float* __restrict__ bk,
    float* __restrict__ M, float* __restrict__ w1, float* __restrict__ w2,
    float* __restrict__ cqk) {
  const int i = blockIdx.x, j = threadIdx.x;
  const int wv = j >> 6, lane = j & 63;
  __shared__ float rowq[Hq];
  __shared__ float redA[4], redB[4], redC[4];
  rowq[j] = Wq[i * Hq + j];
  __syncthreads();
  float acc = 0.f;
  const float* wkr = Wk + (size_t)j * Hq;
  for (int h = 0; h < Hq; h += 4) {
    const float4 a = *reinterpret_cast<const float4*>(&rowq[h]);
    const float4 bb = *reinterpret_cast<const float4*>(&wkr[h]);
    acc = fmaf(a.x, bb.x, fmaf(a.y, bb.y, fmaf(a.z, bb.z, fmaf(a.w, bb.w, acc))));
  }
  M[i * Hq + j] = acc;
  float p1 = rowq[j] * bk[j];
  float p2 = Wk[(size_t)i * Hq + j] * bq[j];
  float p3 = bq[j] * bk[j];
  p1 = waveReduceSum(p1);
  p2 = waveReduceSum(p2);
  p3 = waveReduceSum(p3);
  if (lane == 0) { redA[wv] = p1; redB[wv] = p2; redC[wv] = p3; }
  __syncthreads();
  if (j == 0) {
    w1[i] = redA[0] + redA[1] + redA[2] + redA[3];
    w2[i] = redB[0] + redB[1] + redB[2] + redB[3];
    if (i == 0) *cqk = redC[0] + redC[1] + redC[2] + redC[3];
  }
}

// ---------------------------------------------------------------------------
// Split + transpose weights to N-major bf16 hi/lo: WcT[c][n][k], MT[n][k], WvT[n][k]
// ---------------------------------------------------------------------------
__global__ void k_prep(const float* __restrict__ Wc, const float* __restrict__ M,
                       const float* __restrict__ Wv,
                       unsigned short* __restrict__ WcTh, unsigned short* __restrict__ WcTl,
                       unsigned short* __restrict__ MTh, unsigned short* __restrict__ MTl,
                       unsigned short* __restrict__ WvTh, unsigned short* __restrict__ WvTl) {
  const int NW = Cq * Hq * Hq;
  const int NT = NW + 2 * Hq * Hq;
  for (int idx = blockIdx.x * blockDim.x + threadIdx.x; idx < NT;
       idx += gridDim.x * blockDim.x) {
    if (idx < NW) {
      const int c = idx >> 16, rem = idx & 65535, n = rem >> 8, k = rem & 255;
      const float v = Wc[(size_t)c * 65536 + k * 256 + n];
      const unsigned short hb = f2bf(v);
      WcTh[idx] = hb;
      WcTl[idx] = f2bf(v - bfu(hb));
    } else {
      const int r = idx - NW;
      if (r < 65536) {
        const int n = r >> 8, k = r & 255;
        const float v = M[k * 256 + n];
        const unsigned short hb = f2bf(v);
        MTh[r] = hb;
        MTl[r] = f2bf(v - bfu(hb));
      } else {
        const int r2 = r - 65536;
        const int n = r2 >> 8, k = r2 & 255;
        const float v = Wv[k * 256 + n];
        const unsigned short hb = f2bf(v);
        WvTh[r2] = hb;
        WvTl[r2] = f2bf(v - bfu(hb));
      }
    }
  }
}

// ---------------------------------------------------------------------------
// GEMM1 (MFMA, split-3): Z = vis @ Wc[c] + bc ; LN ; relu ; X' = x + .
// writes X' hi/lo bf16, u = X'.w1, vv = X'.w2
// grid (B/32, C), 256 thr = 4 waves; wave w: cols [64w,64w+64), 2 m-tiles
// ---------------------------------------------------------------------------
__global__ __launch_bounds__(256) void k_gemm1(
    const unsigned short* __restrict__ vish, const unsigned short* __restrict__ visl,
    const unsigned short* __restrict__ WcTh, const unsigned short* __restrict__ WcTl,
    const float* __restrict__ x, const float* __restrict__ bc,
    const float* __restrict__ gc, const float* __restrict__ bec,
    const float* __restrict__ w1, const float* __restrict__ w2,
    unsigned short* __restrict__ Xph, unsigned short* __restrict__ Xpl,
    float* __restrict__ u, float* __restrict__ vv) {
  const int c = blockIdx.y;
  const int b0 = blockIdx.x * 32;
  const int tid = threadIdx.x;
  const int wvi = tid >> 6, lane = tid & 63;
  const int l15 = lane & 15, l4 = lane >> 4;

  __shared__ float Zs[32][264];

  f32x4 acc[2][4];
#pragma unroll
  for (int m = 0; m < 2; m++)
#pragma unroll
    for (int n = 0; n < 4; n++) acc[m][n] = (f32x4){0.f, 0.f, 0.f, 0.f};

  const unsigned short* Bh = WcTh + (size_t)c * Hq * Hq;
  const unsigned short* Bl = WcTl + (size_t)c * Hq * Hq;

  for (int kk = 0; kk < Hq; kk += 32) {
    const int ko = kk + l4 * 8;
    s16x8 ah[2], al[2], bh[4], bl[4];
#pragma unroll
    for (int m = 0; m < 2; m++) {
      const int row = b0 + m * 16 + l15;
      ah[m] = *reinterpret_cast<const s16x8*>(vish + (size_t)row * Hq + ko);
      al[m] = *reinterpret_cast<const s16x8*>(visl + (size_t)row * Hq + ko);
    }
#pragma unroll
    for (int n = 0; n < 4; n++) {
      const int col = wvi * 64 + n * 16 + l15;
      bh[n] = *reinterpret_cast<const s16x8*>(Bh + (size_t)col * Hq + ko);
      bl[n] = *reinterpret_cast<const s16x8*>(Bl + (size_t)col * Hq + ko);
    }
#pragma unroll
    for (int m = 0; m < 2; m++)
#pragma unroll
      for (int n = 0; n < 4; n++) {
        acc[m][n] = __builtin_amdgcn_mfma_f32_16x16x32_bf16(ah[m], bh[n], acc[m][n], 0, 0, 0);
        acc[m][n] = __builtin_amdgcn_mfma_f32_16x16x32_bf16(ah[m], bl[n], acc[m][n], 0, 0, 0);
        acc[m][n] = __builtin_amdgcn_mfma_f32_16x16x32_bf16(al[m], bh[n], acc[m][n], 0, 0, 0);
      }
  }

  // D layout: col = lane&15 (+16n+64w), row = (lane>>4)*4 + r (+16m)
#pragma unroll
  for (int m = 0; m < 2; m++)
#pragma unroll
    for (int n = 0; n < 4; n++) {
      const int col = wvi * 64 + n * 16 + l15;
      const float bcv = bc[c * Hq + col];
#pragma unroll
      for (int r = 0; r < 4; r++)
        Zs[m * 16 + l4 * 4 + r][col] = acc[m][n][r] + bcv;
    }
  __syncthreads();

  // LN + relu + add x + split; 8 threads per row, strided 4-col chunks
  const int row = tid >> 3, sub = tid & 7;
  const int grow = b0 + row;
  const size_t xrow = ((size_t)grow * Cq + c) * Hq;
  float sum = 0.f, sumsq = 0.f;
#pragma unroll
  for (int k = 0; k < 8; k++) {
    const float4 z = *reinterpret_cast<const float4*>(&Zs[row][sub * 4 + k * 32]);
    sum += z.x + z.y + z.z + z.w;
    sumsq += z.x * z.x + z.y * z.y + z.z * z.z + z.w * z.w;
  }
#pragma unroll
  for (int msk = 4; msk >= 1; msk >>= 1) {
    sum += __shfl_xor(sum, msk);
    sumsq += __shfl_xor(sumsq, msk);
  }
  const float mean = sum * (1.0f / Hq);
  const float var = sumsq * (1.0f / Hq) - mean * mean;
  const float inv = rsqrtf(var + EPS);

  float pu = 0.f, pv = 0.f;
#pragma unroll
  for (int k = 0; k < 8; k++) {
    const int col = sub * 4 + k * 32;
    const float4 z = *reinterpret_cast<const float4*>(&Zs[row][col]);
    const float4 xv = *reinterpret_cast<const float4*>(&x[xrow + col]);
    const float zz[4] = {z.x, z.y, z.z, z.w};
    const float xr[4] = {xv.x, xv.y, xv.z, xv.w};
    s16x4 hh, ll;
#pragma unroll
    for (int e = 0; e < 4; e++) {
      float t = (zz[e] - mean) * inv * gc[c * Hq + col + e] + bec[c * Hq + col + e];
      t = fmaxf(t, 0.f);
      const float xp = xr[e] + t;
      const unsigned short hb = f2bf(xp);
      const float hf = bfu(hb);
      hh[e] = (short)hb;
      ll[e] = (short)f2bf(xp - hf);
      pu = fmaf(xp, w1[col + e], pu);
      pv = fmaf(xp, w2[col + e], pv);
    }
    *reinterpret_cast<s16x4*>(Xph + xrow + col) = hh;
    *reinterpret_cast<s16x4*>(Xpl + xrow + col) = ll;
  }
#pragma unroll
  for (int msk = 4; msk >= 1; msk >>= 1) {
    pu += __shfl_xor(pu, msk);
    pv += __shfl_xor(pv, msk);
  }
  if (sub == 0) {
    u[(size_t)grow * Cq + c] = pu;
    vv[(size_t)grow * Cq + c] = pv;
  }
}

// ---------------------------------------------------------------------------
// GEMM2 (MFMA): mode 0: XM = X' @ M (split-3, fp32 out)
//               mode 1: V  = X' @ Wv + bv (split-2, bf16 out)
// grid (R/32, 2)
// ---------------------------------------------------------------------------
__global__ __launch_bounds__(256) void k_gemm2(
    const unsigned short* __restrict__ Xph, const unsigned short* __restrict__ Xpl,
    const unsigned short* __restrict__ MTh, const unsigned short* __restrict__ MTl,
    const unsigned short* __restrict__ WvTh, const unsigned short* __restrict__ WvTl,
    const float* __restrict__ bv, float* __restrict__ XM,
    unsigned short* __restrict__ Vb) {
  const int mode = blockIdx.y;
  const int r0 = blockIdx.x * 32;
  const int tid = threadIdx.x;
  const int wvi = tid >> 6, lane = tid & 63;
  const int l15 = lane & 15, l4 = lane >> 4;

  const unsigned short* Bh = mode ? WvTh : MTh;
  const unsigned short* Bl = mode ? WvTl : MTl;

  f32x4 acc[2][4];
#pragma unroll
  for (int m = 0; m < 2; m++)
#pragma unroll
    for (int n = 0; n < 4; n++) acc[m][n] = (f32x4){0.f, 0.f, 0.f, 0.f};

  for (int kk = 0; kk < Hq; kk += 32) {
    const int ko = kk + l4 * 8;
    s16x8 ah[2], al[2], bh[4], bl[4];
#pragma unroll
    for (int m = 0; m < 2; m++) {
      const size_t row = (size_t)(r0 + m * 16 + l15) * Hq + ko;
      ah[m] = *reinterpret_cast<const s16x8*>(Xph + row);
      al[m] = *reinterpret_cast<const s16x8*>(Xpl + row);
    }
#pragma unroll
    for (int n = 0; n < 4; n++) {
      const int col = wvi * 64 + n * 16 + l15;
      bh[n] = *reinterpret_cast<const s16x8*>(Bh + (size_t)col * Hq + ko);
      if (mode == 0) bl[n] = *reinterpret_cast<const s16x8*>(Bl + (size_t)col * Hq + ko);
    }
    if (mode == 0) {
#pragma unroll
      for (int m = 0; m < 2; m++)
#pragma unroll
        for (int n = 0; n < 4; n++) {
          acc[m][n] = __builtin_amdgcn_mfma_f32_16x16x32_bf16(ah[m], bh[n], acc[m][n], 0, 0, 0);
          acc[m][n] = __builtin_amdgcn_mfma_f32_16x16x32_bf16(ah[m], bl[n], acc[m][n], 0, 0, 0);
          acc[m][n] = __builtin_amdgcn_mfma_f32_16x16x32_bf16(al[m], bh[n], acc[m][n], 0, 0, 0);
        }
    } else {
#pragma unroll
      for (int m = 0; m < 2; m++)
#pragma unroll
        for (int n = 0; n < 4; n++) {
          acc[m][n] = __builtin_amdgcn_mfma_f32_16x16x32_bf16(ah[m], bh[n], acc[m][n], 0, 0, 0);
          acc[m][n] = __builtin_amdgcn_mfma_f32_16x16x32_bf16(al[m], bh[n], acc[m][n], 0, 0, 0);
        }
    }
  }

#pragma unroll
  for (int m = 0; m < 2; m++)
#pragma unroll
    for (int n = 0; n < 4; n++) {
      const int col = wvi * 64 + n * 16 + l15;
#pragma unroll
      for (int r = 0; r < 4; r++) {
        const size_t rowg = (size_t)(r0 + m * 16 + l4 * 4 + r) * Hq + col;
        if (mode == 0) XM[rowg] = acc[m][n][r];
        else           Vb[rowg] = f2bf(acc[m][n][r] + bv[col]);
      }
    }
}

// ---------------------------------------------------------------------------
// K3 (fused attn + out-proj): per b.
// scores = XM . X'^T + u_i + vv_j + cqk, *SCALE, >THR mask, *label, softmax,
// O = attn @ V (chunked), out = O @ Wo + bo (per-thread col accumulator)
// ---------------------------------------------------------------------------
__global__ __launch_bounds__(256) void k_attn(
    const float* __restrict__ XM, const unsigned short* __restrict__ Xph,
    const unsigned short* __restrict__ Xpl, const unsigned short* __restrict__ Vb,
    const int* __restrict__ labels, const float* __restrict__ u,
    const float* __restrict__ vvv, const float* __restrict__ cqk,
    const float* __restrict__ Wo, const float* __restrict__ bo,
    float* __restrict__ out) {
  __shared__ float attn_s[80 * 81];
  __shared__ float stage[2 * 80 * 33];  // qs|ks during scores; vs (80*64) during PV
  __shared__ float Oc[80 * 68];
  float* qs = stage;
  float* ks = stage + 80 * 33;
  float* vs = stage;

  const int b = blockIdx.x;
  const int t = threadIdx.x, tx = t & 15, ty = t >> 4;
  const size_t base = (size_t)b * Cq * Hq;

  float s[5][5];
#pragma unroll
  for (int i = 0; i < 5; i++)
#pragma unroll
    for (int j = 0; j < 5; j++) s[i][j] = 0.f;

  for (int kk = 0; kk < Hq; kk += 32) {
    for (int i = t; i < 80 * 8; i += 256) {
      const int row = i >> 3, c4 = (i & 7) * 4;
      const size_t g = base + (size_t)row * Hq + kk + c4;
      const float4 q4 = *reinterpret_cast<const float4*>(&XM[g]);
      float* qd = &qs[row * 33 + c4];
      qd[0] = q4.x; qd[1] = q4.y; qd[2] = q4.z; qd[3] = q4.w;
      const uint2 hb = *reinterpret_cast<const uint2*>(&Xph[g]);
      const uint2 lb = *reinterpret_cast<const uint2*>(&Xpl[g]);
      float* kd = &ks[row * 33 + c4];
      kd[0] = bfu((unsigned short)(hb.x & 0xffffu)) + bfu((unsigned short)(lb.x & 0xffffu));
      kd[1] = bfu((unsigned short)(hb.x >> 16))     + bfu((unsigned short)(lb.x >> 16));
      kd[2] = bfu((unsigned short)(hb.y & 0xffffu)) + bfu((unsigned short)(lb.y & 0xffffu));
      kd[3] = bfu((unsigned short)(hb.y >> 16))     + bfu((unsigned short)(lb.y >> 16));
    }
    __syncthreads();
#pragma unroll
    for (int k = 0; k < 32; k++) {
      float qv[5], kv[5];
#pragma unroll
      for (int i = 0; i < 5; i++) qv[i] = qs[(ty + 16 * i) * 33 + k];
#pragma unroll
      for (int j = 0; j < 5; j++) kv[j] = ks[(tx + 16 * j) * 33 + k];
#pragma unroll
      for (int i = 0; i < 5; i++)
#pragma unroll
        for (int j = 0; j < 5; j++) s[i][j] = fmaf(qv[i], kv[j], s[i][j]);
    }
    __syncthreads();
  }

  const float cq = *cqk;
  float ui[5], vj[5], lm[5];
#pragma unroll
  for (int i = 0; i < 5; i++) ui[i] = u[b * Cq + ty + 16 * i];
#pragma unroll
  for (int j = 0; j < 5; j++) {
    vj[j] = vvv[b * Cq + tx + 16 * j];
    lm[j] = (float)labels[b * Cq + tx + 16 * j] * 0.8f + 0.2f;
  }
#pragma unroll
  for (int i = 0; i < 5; i++)
#pragma unroll
    for (int j = 0; j < 5; j++) {
      float sc = (s[i][j] + ui[i] + vj[j] + cq) * SCALE;
      sc = (sc > THR) ? sc : 0.0f;
      s[i][j] = sc * lm[j];
    }

  // softmax along d (16 lanes x 5 cols per row)
#pragma unroll
  for (int i = 0; i < 5; i++) {
    float m = s[i][0];
#pragma unroll
    for (int j = 1; j < 5; j++) m = fmaxf(m, s[i][j]);
#pragma unroll
    for (int msk = 8; msk >= 1; msk >>= 1) m = fmaxf(m, __shfl_xor(m, msk));
    float sum = 0.f;
#pragma unroll
    for (int j = 0; j < 5; j++) {
      const float e = expf(s[i][j] - m);
      s[i][j] = e;
      sum += e;
    }
#pragma unroll
    for (int msk = 8; msk >= 1; msk >>= 1) sum += __shfl_xor(sum, msk);
    const float inv = 1.0f / sum;
#pragma unroll
    for (int j = 0; j < 5; j++)
      attn_s[(ty + 16 * i) * 81 + tx + 16 * j] = s[i][j] * inv;
  }
  __syncthreads();

  float outacc[80];
#pragma unroll
  for (int r = 0; r < 80; r++) outacc[r] = 0.f;

  for (int hc = 0; hc < 4; hc++) {
    const int h0 = hc * 64;
    // stage V chunk (bf16 -> f32)
    for (int i = t; i < 80 * 16; i += 256) {
      const int row = i >> 4, c4 = (i & 15) * 4;
      const uint2 vb2 = *reinterpret_cast<const uint2*>(&Vb[base + (size_t)row * Hq + h0 + c4]);
      float* vd = &vs[row * 64 + c4];
      vd[0] = bfu((unsigned short)(vb2.x & 0xffffu));
      vd[1] = bfu((unsigned short)(vb2.x >> 16));
      vd[2] = bfu((unsigned short)(vb2.y & 0xffffu));
      vd[3] = bfu((unsigned short)(vb2.y >> 16));
    }
    __syncthreads();   // A

    float o[5][4];
#pragma unroll
    for (int i = 0; i < 5; i++)
#pragma unroll
      for (int jj = 0; jj < 4; jj++) o[i][jj] = 0.f;
    for (int d = 0; d < Cq; d++) {
      float av[5], vv4[4];
#pragma unroll
      for (int i = 0; i < 5; i++) av[i] = attn_s[(ty + 16 * i) * 81 + d];
#pragma unroll
      for (int jj = 0; jj < 4; jj++) vv4[jj] = vs[d * 64 + tx + 16 * jj];
#pragma unroll
      for (int i = 0; i < 5; i++)
#pragma unroll
        for (int jj = 0; jj < 4; jj++) o[i][jj] = fmaf(av[i], vv4[jj], o[i][jj]);
    }
#pragma unroll
    for (int i = 0; i < 5; i++)
#pragma unroll
      for (int jj = 0; jj < 4; jj++)
        Oc[(ty + 16 * i) * 68 + tx + 16 * jj] = o[i][jj];
    __syncthreads();   // B

    // fused out-proj partial: thread t = output col h
    for (int k = 0; k < 64; k += 8) {
      float w[8];
#pragma unroll
      for (int e = 0; e < 8; e++) w[e] = Wo[(size_t)(h0 + k + e) * Hq + t];
#pragma unroll
      for (int r = 0; r < 80; r++) {
        const float4 a = *reinterpret_cast<const float4*>(&Oc[r * 68 + k]);
        const float4 b4 = *reinterpret_cast<const float4*>(&Oc[r * 68 + k + 4]);
        float acc = outacc[r];
        acc = fmaf(a.x, w[0], acc);
        acc = fmaf(a.y, w[1], acc);
        acc = fmaf(a.z, w[2], acc);
        acc = fmaf(a.w, w[3], acc);
        acc = fmaf(b4.x, w[4], acc);
        acc = fmaf(b4.y, w[5], acc);
        acc = fmaf(b4.z, w[6], acc);
        acc = fmaf(b4.w, w[7], acc);
        outacc[r] = acc;
      }
    }
    __syncthreads();   // before next chunk's stage overwrites vs / PV rewrites Oc
  }

  const float bov = bo[t];
#pragma unroll
  for (int r = 0; r < 80; r++)
    out[((size_t)b * Cq + r) * Hq + t] = outacc[r] + bov;
}

// ---------------------------------------------------------------------------
extern "C" void kernel_launch(void* const* d_in, const int* in_sizes, int n_in,
                              void* d_out, int out_size, void* d_ws, size_t ws_size,
                              hipStream_t stream) {
  const float* x   = (const float*)d_in[0];
  const float* vf  = (const float*)d_in[1];
  const int*   lab = (const int*)d_in[2];
  const float* Wp  = (const float*)d_in[3];
  const float* bp  = (const float*)d_in[4];
  const float* gp  = (const float*)d_in[5];
  const float* bep = (const float*)d_in[6];
  const float* Wc  = (const float*)d_in[7];
  const float* bc  = (const float*)d_in[8];
  const float* gc  = (const float*)d_in[9];
  const float* bec = (const float*)d_in[10];
  const float* Wq  = (const float*)d_in[11];
  const float* bq_ = (const float*)d_in[12];
  const float* Wk  = (const float*)d_in[13];
  const float* bk_ = (const float*)d_in[14];
  const float* Wv  = (const float*)d_in[15];
  const float* bv_ = (const float*)d_in[16];
  const float* Wo  = (const float*)d_in[17];
  const float* bo_ = (const float*)d_in[18];
  float* out = (float*)d_out;
  (void)ws_size; (void)in_sizes; (void)n_in; (void)out_size;

  char* W = (char*)d_ws;
  unsigned short* Xph  = (unsigned short*)(W + 0);          // 20,971,520 B
  unsigned short* Xpl  = (unsigned short*)(W + 20971520);   // 20,971,520 B
  unsigned short* WcTh = (unsigned short*)(W + 41943040);   // 10,485,760 B
  unsigned short* WcTl = (unsigned short*)(W + 52428800);   // 10,485,760 B
  unsigned short* Vb   = (unsigned short*)(W + 41943040);   // aliases WcT (dead after gemm1)
  unsigned short* vish = (unsigned short*)(W + 62914560);   // 262,144 B
  unsigned short* visl = (unsigned short*)(W + 63176704);   // 262,144 B
  unsigned short* MTh  = (unsigned short*)(W + 63438848);   // 131,072 B
  unsigned short* MTl  = (unsigned short*)(W + 63569920);   // 131,072 B
  unsigned short* WvTh = (unsigned short*)(W + 63700992);   // 131,072 B
  unsigned short* WvTl = (unsigned short*)(W + 63832064);   // 131,072 B
  float* Mf   = (float*)(W + 63963136);                     // 262,144 B
  float* w1   = (float*)(W + 64225280);                     // 1,024 B
  float* w2   = (float*)(W + 64226304);                     // 1,024 B
  float* cqk  = (float*)(W + 64227328);                     // 256 B
  float* u    = (float*)(W + 64227584);                     // 163,840 B
  float* vvv  = (float*)(W + 64391424);                     // 163,840 B
  float* XM   = (float*)(W + 64555264);                     // 41,943,040 B -> total 106,498,304 B

  k_visproj<<<Bq, 256, 0, stream>>>(vf, Wp, bp, gp, bep, vish, visl);
  k_matmulM<<<Hq, 256, 0, stream>>>(Wq, Wk, bq_, bk_, Mf, w1, w2, cqk);
  k_prep<<<2048, 256, 0, stream>>>(Wc, Mf, Wv, WcTh, WcTl, MTh, MTl, WvTh, WvTl);
  k_gemm1<<<dim3(Bq / 32, Cq), 256, 0, stream>>>(vish, visl, WcTh, WcTl, x, bc, gc,
                                                 bec, w1, w2, Xph, Xpl, u, vvv);
  k_gemm2<<<dim3(Rq / 32, 2), 256, 0, stream>>>(Xph, Xpl, MTh, MTl, WvTh, WvTl,
                                                bv_, XM, Vb);
  k_attn<<<Bq, 256, 0, stream>>>(XM, Xph, Xpl, Vb, lab, u, vvv, cqk, Wo, bo_, out);
}

// Round 3
// 353.594 us; speedup vs baseline: 2.1752x; 1.5476x over previous
//
#include <hip/hip_runtime.h>
#include <hip/hip_bf16.h>
#include <math.h>

#define Bq 512
#define Cq 80
#define Fq 768
#define Hq 256
#define Rq (Bq*Cq)

constexpr float EPS   = 1e-5f;
constexpr float THR   = 0.5f;
constexpr float SCALE = 0.0625f;   // 1/sqrt(256)

using f32x4 = __attribute__((ext_vector_type(4))) float;
using s16x8 = __attribute__((ext_vector_type(8))) short;
using s16x4 = __attribute__((ext_vector_type(4))) short;

#define MFMA16 __builtin_amdgcn_mfma_f32_16x16x32_bf16

__device__ __forceinline__ float waveReduceSum(float v) {
#pragma unroll
  for (int m = 32; m >= 1; m >>= 1) v += __shfl_xor(v, m);
  return v;
}

__device__ __forceinline__ float bfu(unsigned short v) {
  return __uint_as_float(((unsigned)v) << 16);
}

__device__ __forceinline__ unsigned short f2bf(float f) {
  __hip_bfloat16 h = __float2bfloat16(f);   // RNE
  return *reinterpret_cast<unsigned short*>(&h);
}

// ---------------------------------------------------------------------------
// K1: vis = relu(LN(vf @ Wp + bp)) -> split bf16 hi/lo
// ---------------------------------------------------------------------------
__global__ __launch_bounds__(256) void k_visproj(
    const float* __restrict__ vf, const float* __restrict__ Wp,
    const float* __restrict__ bp, const float* __restrict__ gp,
    const float* __restrict__ bep,
    unsigned short* __restrict__ vish, unsigned short* __restrict__ visl) {
  __shared__ float vfs[Fq];
  __shared__ float red[4];
  const int b = blockIdx.x, h = threadIdx.x;
  for (int i = h; i < Fq; i += 256) vfs[i] = vf[b * Fq + i];
  __syncthreads();

  float acc = bp[h];
  for (int f = 0; f < Fq; f++) acc = fmaf(vfs[f], Wp[f * Hq + h], acc);

  const int w = h >> 6, lane = h & 63;
  float s = waveReduceSum(acc);
  if (lane == 0) red[w] = s;
  __syncthreads();
  const float mean = (red[0] + red[1] + red[2] + red[3]) * (1.0f / Hq);
  __syncthreads();
  const float d = acc - mean;
  s = waveReduceSum(d * d);
  if (lane == 0) red[w] = s;
  __syncthreads();
  const float var = (red[0] + red[1] + red[2] + red[3]) * (1.0f / Hq);
  float y = d * rsqrtf(var + EPS) * gp[h] + bep[h];
  y = fmaxf(y, 0.0f);
  const unsigned short hb = f2bf(y);
  vish[b * Hq + h] = hb;
  visl[b * Hq + h] = f2bf(y - bfu(hb));
}

// ---------------------------------------------------------------------------
// M = Wq @ Wk^T ; w1 = Wq@bk ; w2 = Wk@bq ; cqk = bq.bk
// ---------------------------------------------------------------------------
__global__ __launch_bounds__(256) void k_matmulM(
    const float* __restrict__ Wq, const float* __restrict__ Wk,
    const float* __restrict__ bq, const float* __restrict__ bk,
    float* __restrict__ M, float* __restrict__ w1, float* __restrict__ w2,
    float* __restrict__ cqk) {
  const int i = blockIdx.x, j = threadIdx.x;
  const int wv = j >> 6, lane = j & 63;
  __shared__ float rowq[Hq];
  __shared__ float redA[4], redB[4], redC[4];
  rowq[j] = Wq[i * Hq + j];
  __syncthreads();
  float acc = 0.f;
  const float* wkr = Wk + (size_t)j * Hq;
  for (int h = 0; h < Hq; h += 4) {
    const float4 a = *reinterpret_cast<const float4*>(&rowq[h]);
    const float4 bb = *reinterpret_cast<const float4*>(&wkr[h]);
    acc = fmaf(a.x, bb.x, fmaf(a.y, bb.y, fmaf(a.z, bb.z, fmaf(a.w, bb.w, acc))));
  }
  M[i * Hq + j] = acc;
  float p1 = rowq[j] * bk[j];
  float p2 = Wk[(size_t)i * Hq + j] * bq[j];
  float p3 = bq[j] * bk[j];
  p1 = waveReduceSum(p1);
  p2 = waveReduceSum(p2);
  p3 = waveReduceSum(p3);
  if (lane == 0) { redA[wv] = p1; redB[wv] = p2; redC[wv] = p3; }
  __syncthreads();
  if (j == 0) {
    w1[i] = redA[0] + redA[1] + redA[2] + redA[3];
    w2[i] = redB[0] + redB[1] + redB[2] + redB[3];
    if (i == 0) *cqk = redC[0] + redC[1] + redC[2] + redC[3];
  }
}

// ---------------------------------------------------------------------------
// Split + transpose weights to N-major bf16: WcT h/l, MT h/l, WvT h/l, WoT (single)
// ---------------------------------------------------------------------------
__global__ void k_prep(const float* __restrict__ Wc, const float* __restrict__ M,
                       const float* __restrict__ Wv, const float* __restrict__ Wo,
                       unsigned short* __restrict__ WcTh, unsigned short* __restrict__ WcTl,
                       unsigned short* __restrict__ MTh, unsigned short* __restrict__ MTl,
                       unsigned short* __restrict__ WvTh, unsigned short* __restrict__ WvTl,
                       unsigned short* __restrict__ WoT) {
  const int NW = Cq * Hq * Hq;
  const int NT = NW + 3 * Hq * Hq;
  for (int idx = blockIdx.x * blockDim.x + threadIdx.x; idx < NT;
       idx += gridDim.x * blockDim.x) {
    if (idx < NW) {
      const int c = idx >> 16, rem = idx & 65535, n = rem >> 8, k = rem & 255;
      const float v = Wc[(size_t)c * 65536 + k * 256 + n];
      const unsigned short hb = f2bf(v);
      WcTh[idx] = hb;
      WcTl[idx] = f2bf(v - bfu(hb));
    } else {
      const int r = idx - NW;
      if (r < 65536) {
        const int n = r >> 8, k = r & 255;
        const float v = M[k * 256 + n];
        const unsigned short hb = f2bf(v);
        MTh[r] = hb;
        MTl[r] = f2bf(v - bfu(hb));
      } else if (r < 131072) {
        const int r2 = r - 65536;
        const int n = r2 >> 8, k = r2 & 255;
        const float v = Wv[k * 256 + n];
        const unsigned short hb = f2bf(v);
        WvTh[r2] = hb;
        WvTl[r2] = f2bf(v - bfu(hb));
      } else {
        const int r3 = r - 131072;
        const int n = r3 >> 8, k = r3 & 255;
        WoT[r3] = f2bf(Wo[k * 256 + n]);
      }
    }
  }
}

// ---------------------------------------------------------------------------
// GEMM1 (MFMA, split-3): Z = vis @ Wc[c] + bc ; LN ; relu ; X' = x + .
// writes X' hi/lo bf16, u = X'.w1, vv = X'.w2
// ---------------------------------------------------------------------------
__global__ __launch_bounds__(256) void k_gemm1(
    const unsigned short* __restrict__ vish, const unsigned short* __restrict__ visl,
    const unsigned short* __restrict__ WcTh, const unsigned short* __restrict__ WcTl,
    const float* __restrict__ x, const float* __restrict__ bc,
    const float* __restrict__ gc, const float* __restrict__ bec,
    const float* __restrict__ w1, const float* __restrict__ w2,
    unsigned short* __restrict__ Xph, unsigned short* __restrict__ Xpl,
    float* __restrict__ u, float* __restrict__ vv) {
  const int c = blockIdx.y;
  const int b0 = blockIdx.x * 32;
  const int tid = threadIdx.x;
  const int wvi = tid >> 6, lane = tid & 63;
  const int l15 = lane & 15, l4 = lane >> 4;

  __shared__ float Zs[32][264];

  f32x4 acc[2][4];
#pragma unroll
  for (int m = 0; m < 2; m++)
#pragma unroll
    for (int n = 0; n < 4; n++) acc[m][n] = (f32x4){0.f, 0.f, 0.f, 0.f};

  const unsigned short* Bh = WcTh + (size_t)c * Hq * Hq;
  const unsigned short* Bl = WcTl + (size_t)c * Hq * Hq;

  for (int kk = 0; kk < Hq; kk += 32) {
    const int ko = kk + l4 * 8;
    s16x8 ah[2], al[2], bh[4], bl[4];
#pragma unroll
    for (int m = 0; m < 2; m++) {
      const int row = b0 + m * 16 + l15;
      ah[m] = *reinterpret_cast<const s16x8*>(vish + (size_t)row * Hq + ko);
      al[m] = *reinterpret_cast<const s16x8*>(visl + (size_t)row * Hq + ko);
    }
#pragma unroll
    for (int n = 0; n < 4; n++) {
      const int col = wvi * 64 + n * 16 + l15;
      bh[n] = *reinterpret_cast<const s16x8*>(Bh + (size_t)col * Hq + ko);
      bl[n] = *reinterpret_cast<const s16x8*>(Bl + (size_t)col * Hq + ko);
    }
#pragma unroll
    for (int m = 0; m < 2; m++)
#pragma unroll
      for (int n = 0; n < 4; n++) {
        acc[m][n] = MFMA16(ah[m], bh[n], acc[m][n], 0, 0, 0);
        acc[m][n] = MFMA16(ah[m], bl[n], acc[m][n], 0, 0, 0);
        acc[m][n] = MFMA16(al[m], bh[n], acc[m][n], 0, 0, 0);
      }
  }

#pragma unroll
  for (int m = 0; m < 2; m++)
#pragma unroll
    for (int n = 0; n < 4; n++) {
      const int col = wvi * 64 + n * 16 + l15;
      const float bcv = bc[c * Hq + col];
#pragma unroll
      for (int r = 0; r < 4; r++)
        Zs[m * 16 + l4 * 4 + r][col] = acc[m][n][r] + bcv;
    }
  __syncthreads();

  const int row = tid >> 3, sub = tid & 7;
  const int grow = b0 + row;
  const size_t xrow = ((size_t)grow * Cq + c) * Hq;
  float sum = 0.f, sumsq = 0.f;
#pragma unroll
  for (int k = 0; k < 8; k++) {
    const float4 z = *reinterpret_cast<const float4*>(&Zs[row][sub * 4 + k * 32]);
    sum += z.x + z.y + z.z + z.w;
    sumsq += z.x * z.x + z.y * z.y + z.z * z.z + z.w * z.w;
  }
#pragma unroll
  for (int msk = 4; msk >= 1; msk >>= 1) {
    sum += __shfl_xor(sum, msk);
    sumsq += __shfl_xor(sumsq, msk);
  }
  const float mean = sum * (1.0f / Hq);
  const float var = sumsq * (1.0f / Hq) - mean * mean;
  const float inv = rsqrtf(var + EPS);

  float pu = 0.f, pv = 0.f;
#pragma unroll
  for (int k = 0; k < 8; k++) {
    const int col = sub * 4 + k * 32;
    const float4 z = *reinterpret_cast<const float4*>(&Zs[row][col]);
    const float4 xv = *reinterpret_cast<const float4*>(&x[xrow + col]);
    const float zz[4] = {z.x, z.y, z.z, z.w};
    const float xr[4] = {xv.x, xv.y, xv.z, xv.w};
    s16x4 hh, ll;
#pragma unroll
    for (int e = 0; e < 4; e++) {
      float t = (zz[e] - mean) * inv * gc[c * Hq + col + e] + bec[c * Hq + col + e];
      t = fmaxf(t, 0.f);
      const float xp = xr[e] + t;
      const unsigned short hb = f2bf(xp);
      const float hf = bfu(hb);
      hh[e] = (short)hb;
      ll[e] = (short)f2bf(xp - hf);
      pu = fmaf(xp, w1[col + e], pu);
      pv = fmaf(xp, w2[col + e], pv);
    }
    *reinterpret_cast<s16x4*>(Xph + xrow + col) = hh;
    *reinterpret_cast<s16x4*>(Xpl + xrow + col) = ll;
  }
#pragma unroll
  for (int msk = 4; msk >= 1; msk >>= 1) {
    pu += __shfl_xor(pu, msk);
    pv += __shfl_xor(pv, msk);
  }
  if (sub == 0) {
    u[(size_t)grow * Cq + c] = pu;
    vv[(size_t)grow * Cq + c] = pv;
  }
}

// ---------------------------------------------------------------------------
// GEMM2 (MFMA): mode 0: XM = X' @ M (split-3) -> bf16 hi/lo
//               mode 1: V  = X' @ Wv + bv (split-2) -> Vt[b][h][c] bf16
// ---------------------------------------------------------------------------
__global__ __launch_bounds__(256) void k_gemm2(
    const unsigned short* __restrict__ Xph, const unsigned short* __restrict__ Xpl,
    const unsigned short* __restrict__ MTh, const unsigned short* __restrict__ MTl,
    const unsigned short* __restrict__ WvTh, const unsigned short* __restrict__ WvTl,
    const float* __restrict__ bv,
    unsigned short* __restrict__ XMh, unsigned short* __restrict__ XMl,
    unsigned short* __restrict__ Vt) {
  const int mode = blockIdx.y;
  const int r0 = blockIdx.x * 32;
  const int tid = threadIdx.x;
  const int wvi = tid >> 6, lane = tid & 63;
  const int l15 = lane & 15, l4 = lane >> 4;

  const unsigned short* Bh = mode ? WvTh : MTh;
  const unsigned short* Bl = mode ? WvTl : MTl;

  f32x4 acc[2][4];
#pragma unroll
  for (int m = 0; m < 2; m++)
#pragma unroll
    for (int n = 0; n < 4; n++) acc[m][n] = (f32x4){0.f, 0.f, 0.f, 0.f};

  for (int kk = 0; kk < Hq; kk += 32) {
    const int ko = kk + l4 * 8;
    s16x8 ah[2], al[2], bh[4], bl[4];
#pragma unroll
    for (int m = 0; m < 2; m++) {
      const size_t row = (size_t)(r0 + m * 16 + l15) * Hq + ko;
      ah[m] = *reinterpret_cast<const s16x8*>(Xph + row);
      al[m] = *reinterpret_cast<const s16x8*>(Xpl + row);
    }
#pragma unroll
    for (int n = 0; n < 4; n++) {
      const int col = wvi * 64 + n * 16 + l15;
      bh[n] = *reinterpret_cast<const s16x8*>(Bh + (size_t)col * Hq + ko);
      if (mode == 0) bl[n] = *reinterpret_cast<const s16x8*>(Bl + (size_t)col * Hq + ko);
    }
    if (mode == 0) {
#pragma unroll
      for (int m = 0; m < 2; m++)
#pragma unroll
        for (int n = 0; n < 4; n++) {
          acc[m][n] = MFMA16(ah[m], bh[n], acc[m][n], 0, 0, 0);
          acc[m][n] = MFMA16(ah[m], bl[n], acc[m][n], 0, 0, 0);
          acc[m][n] = MFMA16(al[m], bh[n], acc[m][n], 0, 0, 0);
        }
    } else {
#pragma unroll
      for (int m = 0; m < 2; m++)
#pragma unroll
        for (int n = 0; n < 4; n++) {
          acc[m][n] = MFMA16(ah[m], bh[n], acc[m][n], 0, 0, 0);
          acc[m][n] = MFMA16(al[m], bh[n], acc[m][n], 0, 0, 0);
        }
    }
  }

#pragma unroll
  for (int m = 0; m < 2; m++)
#pragma unroll
    for (int n = 0; n < 4; n++) {
      const int col = wvi * 64 + n * 16 + l15;
      if (mode == 0) {
#pragma unroll
        for (int r = 0; r < 4; r++) {
          const size_t rowg = (size_t)(r0 + m * 16 + l4 * 4 + r) * Hq + col;
          const unsigned short hb = f2bf(acc[m][n][r]);
          XMh[rowg] = hb;
          XMl[rowg] = f2bf(acc[m][n][r] - bfu(hb));
        }
      } else {
        const float bvv = bv[col];
#pragma unroll
        for (int r = 0; r < 4; r++) {
          const int rowg = r0 + m * 16 + l4 * 4 + r;
          const int bb = rowg / Cq;
          const int cc = rowg - bb * Cq;
          Vt[((size_t)bb * Hq + col) * Cq + cc] = f2bf(acc[m][n][r] + bvv);
        }
      }
    }
}

// ---------------------------------------------------------------------------
// K3 (all-MFMA fused attention + out-proj), one block per b, 5 waves.
// S^T = X'[b] . XM[b]^T (split-3, wave w owns i-cols 16w..16w+15),
// softmax over j in regs (shfl 16/32), P -> LDS bf16, O = P@V (Vt b-frags),
// O -> LDS (wave-local), out = O@WoT + bo.
// ---------------------------------------------------------------------------
__global__ __launch_bounds__(320) void k_attn3(
    const unsigned short* __restrict__ XMh, const unsigned short* __restrict__ XMl,
    const unsigned short* __restrict__ Xph, const unsigned short* __restrict__ Xpl,
    const unsigned short* __restrict__ Vt, const int* __restrict__ labels,
    const float* __restrict__ u, const float* __restrict__ vv,
    const float* __restrict__ cqk, const unsigned short* __restrict__ WoT,
    const float* __restrict__ bo, float* __restrict__ out) {
  __shared__ unsigned short Pl[80][104];    // P, j padded to 96 (zeros)
  __shared__ unsigned short Olds[80][264];  // O bf16, wave-local rows
  __shared__ float us[80], vvs[80], lms[80];

  const int b = blockIdx.x, t = threadIdx.x;
  const int w = t >> 6, lane = t & 63;
  const int l15 = lane & 15, g = lane >> 4;

  if (t < 80) {
    us[t] = u[b * Cq + t];
    vvs[t] = vv[b * Cq + t];
    lms[t] = (float)labels[b * Cq + t] * 0.8f + 0.2f;
  }

  // ---- QK^T: S^T tiles. A = X' rows j (5 m-tiles), B = XM rows i (wave) ----
  f32x4 sacc[5];
#pragma unroll
  for (int mt = 0; mt < 5; mt++) sacc[mt] = (f32x4){0.f, 0.f, 0.f, 0.f};

  const size_t rowB = ((size_t)b * Cq + 16 * w + l15) * Hq;
  for (int kk = 0; kk < 8; kk++) {
    const int ko = kk * 32 + g * 8;
    const s16x8 bh = *reinterpret_cast<const s16x8*>(XMh + rowB + ko);
    const s16x8 bl = *reinterpret_cast<const s16x8*>(XMl + rowB + ko);
#pragma unroll
    for (int mt = 0; mt < 5; mt++) {
      const size_t rowA = ((size_t)b * Cq + 16 * mt + l15) * Hq + ko;
      const s16x8 ah = *reinterpret_cast<const s16x8*>(Xph + rowA);
      const s16x8 al = *reinterpret_cast<const s16x8*>(Xpl + rowA);
      sacc[mt] = MFMA16(ah, bh, sacc[mt], 0, 0, 0);
      sacc[mt] = MFMA16(ah, bl, sacc[mt], 0, 0, 0);
      sacc[mt] = MFMA16(al, bh, sacc[mt], 0, 0, 0);
    }
  }
  __syncthreads();   // us/vvs/lms ready

  // ---- mask + softmax over j (rows of S^T) ----
  const int i = 16 * w + l15;
  const float ui = us[i];
  const float cq = *cqk;
  float p[5][4];
  float mx = -1e30f;
#pragma unroll
  for (int mt = 0; mt < 5; mt++)
#pragma unroll
    for (int r = 0; r < 4; r++) {
      const int j = 16 * mt + 4 * g + r;
      float sc = (sacc[mt][r] + ui + vvs[j] + cq) * SCALE;
      sc = (sc > THR) ? sc : 0.0f;
      sc *= lms[j];
      p[mt][r] = sc;
      mx = fmaxf(mx, sc);
    }
  mx = fmaxf(mx, __shfl_xor(mx, 16));
  mx = fmaxf(mx, __shfl_xor(mx, 32));
  float sum = 0.f;
#pragma unroll
  for (int mt = 0; mt < 5; mt++)
#pragma unroll
    for (int r = 0; r < 4; r++) {
      const float e = __expf(p[mt][r] - mx);
      p[mt][r] = e;
      sum += e;
    }
  sum += __shfl_xor(sum, 16);
  sum += __shfl_xor(sum, 32);
  const float inv = 1.0f / sum;

#pragma unroll
  for (int mt = 0; mt < 5; mt++) {
    uint2 pk;
    pk.x = (unsigned)f2bf(p[mt][0] * inv) | ((unsigned)f2bf(p[mt][1] * inv) << 16);
    pk.y = (unsigned)f2bf(p[mt][2] * inv) | ((unsigned)f2bf(p[mt][3] * inv) << 16);
    *reinterpret_cast<uint2*>(reinterpret_cast<char*>(&Pl[i][0]) + 32 * mt + 8 * g) = pk;
  }
  if (t < 160) {   // zero pad j in [80,96)
    const uint4 z = {0u, 0u, 0u, 0u};
    *reinterpret_cast<uint4*>(reinterpret_cast<char*>(&Pl[t >> 1][0]) + 160 + 16 * (t & 1)) = z;
  }
  __syncthreads();

  // ---- PV: O[16w..16w+16) rows = P @ V ----
  s16x8 pa[3];
#pragma unroll
  for (int ks = 0; ks < 3; ks++)
    pa[ks] = *reinterpret_cast<const s16x8*>(
        reinterpret_cast<const char*>(&Pl[i][0]) + 64 * ks + 16 * g);

  f32x4 oacc[16];
#pragma unroll
  for (int n = 0; n < 16; n++) oacc[n] = (f32x4){0.f, 0.f, 0.f, 0.f};

  const size_t vbase = (size_t)b * Hq * Cq;
#pragma unroll 4
  for (int n = 0; n < 16; n++) {
    const size_t hrow = vbase + (size_t)(16 * n + l15) * Cq + 8 * g;
#pragma unroll
    for (int ks = 0; ks < 3; ks++) {
      const s16x8 vb = *reinterpret_cast<const s16x8*>(Vt + hrow + 32 * ks);
      oacc[n] = MFMA16(pa[ks], vb, oacc[n], 0, 0, 0);
    }
  }

  // ---- O -> LDS (wave-local rows), then out-proj MFMA ----
#pragma unroll
  for (int n = 0; n < 16; n++)
#pragma unroll
    for (int r = 0; r < 4; r++)
      Olds[16 * w + 4 * g + r][16 * n + l15] = f2bf(oacc[n][r]);
  // no cross-wave dependency: each wave reads only its own 16 rows

  f32x4 acc2[16];
#pragma unroll
  for (int n = 0; n < 16; n++) acc2[n] = (f32x4){0.f, 0.f, 0.f, 0.f};

  for (int ks = 0; ks < 8; ks++) {
    const s16x8 af = *reinterpret_cast<const s16x8*>(
        reinterpret_cast<const char*>(&Olds[16 * w + l15][0]) + 64 * ks + 16 * g);
#pragma unroll
    for (int n = 0; n < 16; n++) {
      const s16x8 bf = *reinterpret_cast<const s16x8*>(
          WoT + (size_t)(16 * n + l15) * Hq + 32 * ks + 8 * g);
      acc2[n] = MFMA16(af, bf, acc2[n], 0, 0, 0);
    }
  }

#pragma unroll
  for (int n = 0; n < 16; n++) {
    const float bov = bo[16 * n + l15];
#pragma unroll
    for (int r = 0; r < 4; r++)
      out[((size_t)b * Cq + 16 * w + 4 * g + r) * Hq + 16 * n + l15] =
          acc2[n][r] + bov;
  }
}

// ---------------------------------------------------------------------------
extern "C" void kernel_launch(void* const* d_in, const int* in_sizes, int n_in,
                              void* d_out, int out_size, void* d_ws, size_t ws_size,
                              hipStream_t stream) {
  const float* x   = (const float*)d_in[0];
  const float* vf  = (const float*)d_in[1];
  const int*   lab = (const int*)d_in[2];
  const float* Wp  = (const float*)d_in[3];
  const float* bp  = (const float*)d_in[4];
  const float* gp  = (const float*)d_in[5];
  const float* bep = (const float*)d_in[6];
  const float* Wc  = (const float*)d_in[7];
  const float* bc  = (const float*)d_in[8];
  const float* gc  = (const float*)d_in[9];
  const float* bec = (const float*)d_in[10];
  const float* Wq  = (const float*)d_in[11];
  const float* bq_ = (const float*)d_in[12];
  const float* Wk  = (const float*)d_in[13];
  const float* bk_ = (const float*)d_in[14];
  const float* Wv  = (const float*)d_in[15];
  const float* bv_ = (const float*)d_in[16];
  const float* Wo  = (const float*)d_in[17];
  const float* bo_ = (const float*)d_in[18];
  float* out = (float*)d_out;
  (void)ws_size; (void)in_sizes; (void)n_in; (void)out_size;

  char* W = (char*)d_ws;
  unsigned short* Xph  = (unsigned short*)(W + 0);          // 20,971,520
  unsigned short* Xpl  = (unsigned short*)(W + 20971520);   // 20,971,520
  unsigned short* WcTh = (unsigned short*)(W + 41943040);   // 10,485,760
  unsigned short* WcTl = (unsigned short*)(W + 52428800);   // 10,485,760
  unsigned short* Vt   = (unsigned short*)(W + 41943040);   // aliases WcT (dead after gemm1)
  unsigned short* vish = (unsigned short*)(W + 62914560);   // 262,144
  unsigned short* visl = (unsigned short*)(W + 63176704);   // 262,144
  unsigned short* MTh  = (unsigned short*)(W + 63438848);   // 131,072
  unsigned short* MTl  = (unsigned short*)(W + 63569920);   // 131,072
  unsigned short* WvTh = (unsigned short*)(W + 63700992);   // 131,072
  unsigned short* WvTl = (unsigned short*)(W + 63832064);   // 131,072
  unsigned short* WoT  = (unsigned short*)(W + 63963136);   // 131,072
  float* Mf   = (float*)(W + 64094208);                     // 262,144
  float* w1   = (float*)(W + 64356352);                     // 1,024
  float* w2   = (float*)(W + 64357376);                     // 1,024
  float* cqk  = (float*)(W + 64358400);                     // 256
  float* u    = (float*)(W + 64358656);                     // 163,840
  float* vvv  = (float*)(W + 64522496);                     // 163,840
  unsigned short* XMh = (unsigned short*)(W + 64686336);    // 20,971,520
  unsigned short* XMl = (unsigned short*)(W + 85657856);    // 20,971,520 -> 106,629,376 total

  k_visproj<<<Bq, 256, 0, stream>>>(vf, Wp, bp, gp, bep, vish, visl);
  k_matmulM<<<Hq, 256, 0, stream>>>(Wq, Wk, bq_, bk_, Mf, w1, w2, cqk);
  k_prep<<<2048, 256, 0, stream>>>(Wc, Mf, Wv, Wo, WcTh, WcTl, MTh, MTl,
                                   WvTh, WvTl, WoT);
  k_gemm1<<<dim3(Bq / 32, Cq), 256, 0, stream>>>(vish, visl, WcTh, WcTl, x, bc, gc,
                                                 bec, w1, w2, Xph, Xpl, u, vvv);
  k_gemm2<<<dim3(Rq / 32, 2), 256, 0, stream>>>(Xph, Xpl, MTh, MTl, WvTh, WvTl,
                                                bv_, XMh, XMl, Vt);
  k_attn3<<<Bq, 320, 0, stream>>>(XMh, XMl, Xph, Xpl, Vt, lab, u, vvv, cqk,
                                  WoT, bo_, out);
}